// Round 3
// baseline (1550.416 us; speedup 1.0000x reference)
//
#include <hip/hip_runtime.h>
#include <hip/hip_bf16.h>
#include <cstdint>
#include <cstddef>

#define B_ 2
#define T_ 1024
#define D_ 2048
#define H_ 16
#define DK_ 128
#define DV_ 128
#define ROWS (B_*T_)      // 2048
// Y columns: [q 0:2048 | k 2048:4096 | v 4096:6144 | a 6144:8192 | g 8192:10240 | beta 10240:10256 | pad :10368]
#define NCAT 10368
#define YSTRIDE 10368

typedef __attribute__((ext_vector_type(8))) short bf16x8;
typedef __attribute__((ext_vector_type(4))) float f32x4;

__device__ inline unsigned short f2bf(float f){
    union { float f; unsigned int u; } v; v.f = f;
    unsigned int r = (v.u + 0x7fffu + ((v.u >> 16) & 1u)) >> 16;
    return (unsigned short)r;
}
__device__ inline float sigm(float x){ return 1.0f / (1.0f + __expf(-x)); }

// ---- DPP helpers ----
template<int CTRL>
__device__ __forceinline__ float dpp_add(float x){
    int t = __builtin_amdgcn_update_dpp(0, __builtin_bit_cast(int, x), CTRL, 0xf, 0xf, true);
    return x + __builtin_bit_cast(float, t);
}
// sum over all 64 lanes; result valid in lane 63
__device__ __forceinline__ float wave_sum63(float x){
    x = dpp_add<0x111>(x);   // row_shr:1
    x = dpp_add<0x112>(x);   // row_shr:2
    x = dpp_add<0x114>(x);   // row_shr:4
    x = dpp_add<0x118>(x);   // row_shr:8   lane15/31/47/63 = 16-sums
    x = dpp_add<0x142>(x);   // row_bcast15 lane31 = sum(0..31), lane63 = sum(32..63)
    x = dpp_add<0x143>(x);   // row_bcast31 lane63 = sum(0..63)
    return x;
}

__device__ __forceinline__ void gl2lds16(const void* g, void* l){
    __builtin_amdgcn_global_load_lds((const __attribute__((address_space(1))) void*)g,
                                     (__attribute__((address_space(3))) void*)l, 16, 0, 0);
}

// ---------------- fused fp32 -> bf16 casts (one launch) ----------------
struct Cast8 { const float* p[8]; };  // x, Wq, Wk, Wv, Wa, Wg, Wo, Wb
__global__ void cast_all_kernel(Cast8 args, unsigned short* __restrict__ xb,
                                unsigned short* __restrict__ Wcat,
                                unsigned short* __restrict__ Wob){
    int blk = blockIdx.x;
    if (blk >= 28704) {  // zero-pad rows 10256..10367 of Wcat
        int i = (blk - 28704)*1024 + threadIdx.x*4;
        *(ushort4*)(Wcat + (size_t)10256*2048 + i) = (ushort4){0,0,0,0};
        return;
    }
    const float* src; unsigned short* dst; int i;
    if (blk >= 28672) {  // Wb -> Wcat rows 10240..10255
        i = (blk - 28672)*1024 + threadIdx.x*4;
        src = args.p[7]; dst = Wcat + (size_t)10240*2048;
    } else {
        int seg = blk >> 12;
        i = (blk & 4095)*1024 + threadIdx.x*4;
        src = args.p[seg];
        if (seg == 0)      dst = xb;
        else if (seg <= 5) dst = Wcat + (size_t)(seg-1)*4194304;
        else               dst = Wob;
    }
    float4 f = *(const float4*)(src + i);
    ushort4 u; u.x = f2bf(f.x); u.y = f2bf(f.y); u.z = f2bf(f.z); u.w = f2bf(f.w);
    *(ushort4*)(dst + i) = u;
}

// ---------------- bf16 GEMM (m97-style): C[M,N] = A[M,K]*Bm[N,K]^T ----------------
// global_load_lds width-16 staging, XOR-swizzled col-blocks, 128x128 tile, BK=32.
__global__ __launch_bounds__(256) void gemm_bt(
    const unsigned short* __restrict__ A,
    const unsigned short* __restrict__ Bm,
    float* __restrict__ C, int M, int N, int K,
    int act_start, const float* __restrict__ ba, const float* __restrict__ bbeta)
{
    __shared__ __align__(16) unsigned short lA[128*32];
    __shared__ __align__(16) unsigned short lB[128*32];
    const int tid  = threadIdx.x;
    const int wave = tid >> 6, lane = tid & 63;
    const int quad = lane >> 4, l16 = lane & 15;
    const int wm = wave >> 1, wn = wave & 1;
    const int m0 = blockIdx.y * 128, n0 = blockIdx.x * 128;

    // staging: issue i in {0,1}: chunk = wave*128 + i*64 + lane
    // row = chunk>>2, phys col-block p = chunk&3 holds global col-block p^(row&3)
    const unsigned short* gsrcA[2];
    const unsigned short* gsrcB[2];
    unsigned short* ldst[2];
    #pragma unroll
    for (int i = 0; i < 2; i++) {
        int chunk = wave*128 + i*64 + lane;
        int r = chunk >> 2, p = chunk & 3;
        int gcb = p ^ (r & 3);
        gsrcA[i] = A  + (size_t)(m0 + r)*K + gcb*8;
        gsrcB[i] = Bm + (size_t)(n0 + r)*K + gcb*8;
        ldst[i]  = (unsigned short*)((char*)lA + (size_t)(wave*128 + i*64)*16);  // +lane*16 implicit
    }
    const size_t lBoff = (size_t)((char*)lB - (char*)lA);

    f32x4 acc[4][4];
    #pragma unroll
    for (int i = 0; i < 4; i++)
        #pragma unroll
        for (int j = 0; j < 4; j++) acc[i][j] = (f32x4){0.f,0.f,0.f,0.f};

    for (int k0 = 0; k0 < K; k0 += 32) {
        __syncthreads();   // previous iteration's reads done
        #pragma unroll
        for (int i = 0; i < 2; i++) {
            gl2lds16(gsrcA[i] + k0, ldst[i]);
            gl2lds16(gsrcB[i] + k0, (char*)ldst[i] + lBoff);
        }
        __syncthreads();   // staging complete (vmcnt drained by barrier semantics)
        bf16x8 af[4], bfr[4];
        #pragma unroll
        for (int i = 0; i < 4; i++) {
            int ra = wm*64 + i*16 + l16;
            int rb = wn*64 + i*16 + l16;
            af[i]  = *(const bf16x8*)(&lA[ra*32 + ((quad ^ (ra & 3))*8)]);
            bfr[i] = *(const bf16x8*)(&lB[rb*32 + ((quad ^ (rb & 3))*8)]);
        }
        #pragma unroll
        for (int i = 0; i < 4; i++)
            #pragma unroll
            for (int j = 0; j < 4; j++)
                acc[i][j] = __builtin_amdgcn_mfma_f32_16x16x32_bf16(af[i], bfr[j], acc[i][j], 0, 0, 0);
    }

    #pragma unroll
    for (int i = 0; i < 4; i++) {
        int m = m0 + wm*64 + i*16 + quad*4;
        #pragma unroll
        for (int j = 0; j < 4; j++) {
            int n = n0 + wn*64 + j*16 + l16;
            #pragma unroll
            for (int r = 0; r < 4; r++) {
                float y = acc[i][j][r];
                if (n >= act_start) {
                    float bsum = 0.0f;
                    if (n < 8192) bsum = ba[n - 6144];
                    else if (n >= 10240 && n < 10256) bsum = bbeta[n - 10240];
                    y = sigm(y + bsum);
                }
                C[(size_t)(m + r)*N + n] = y;
            }
        }
    }
}

// ---------------- causal depthwise conv (K=4) + silu + scale ----------------
__global__ void conv_silu_kernel(const float* __restrict__ Y, int col_off,
                                 const float* __restrict__ cw, const float* __restrict__ cb,
                                 float scale, float* __restrict__ out)
{
    int gid = blockIdx.x * blockDim.x + threadIdx.x;  // 32768 total
    int c = gid & 2047;
    int tmp = gid >> 11;
    int tch = tmp & 7;
    int b = tmp >> 3;
    int t0 = tch * 128;
    const float w0 = cw[c*4+0], w1 = cw[c*4+1], w2 = cw[c*4+2], w3 = cw[c*4+3];
    const float bias = cb[c];
    const float* src = Y + (size_t)b*T_*YSTRIDE + col_off + c;
    float* dst = out + (size_t)b*T_*2048 + c;
    float y0 = (t0 >= 3) ? src[(size_t)(t0-3)*YSTRIDE] : 0.f;
    float y1 = (t0 >= 2) ? src[(size_t)(t0-2)*YSTRIDE] : 0.f;
    float y2 = (t0 >= 1) ? src[(size_t)(t0-1)*YSTRIDE] : 0.f;
    for (int t = t0; t < t0 + 128; t++) {
        float y3 = src[(size_t)t*YSTRIDE];
        float s = fmaf(w0,y0, fmaf(w1,y1, fmaf(w2,y2, fmaf(w3,y3, bias))));
        float r = s * (1.0f/(1.0f + __expf(-s))) * scale;
        dst[(size_t)t*2048] = r;
        y0 = y1; y1 = y2; y2 = y3;
    }
}

// ---------------- gated delta recurrence: 1 v-row per wave ----------------
// 1024 blocks x 4 waves = 4096 waves; lane owns 2 k-elems; DPP reduce + readlane bcast.
__global__ __launch_bounds__(256) void recurrence_kernel(
    const float* __restrict__ q, const float* __restrict__ k, const float* __restrict__ v,
    const float* __restrict__ a, const float* __restrict__ beta, float* __restrict__ o)
{
    const int blk = blockIdx.x;           // bh(32) x rowgrp(32)
    const int rowgrp = blk & 31;
    const int bh = blk >> 5;
    const int h = bh & 15, b = bh >> 4;
    const int lane = threadIdx.x & 63;
    const int wave = threadIdx.x >> 6;
    const int vrow = rowgrp*4 + wave;     // 0..127
    const size_t rbase = (size_t)b * T_;
    const float2* kp = (const float2*)(k + rbase*2048 + (size_t)h*128) + lane;  // step stride 1024 float2
    const float2* qp = (const float2*)(q + rbase*2048 + (size_t)h*128) + lane;
    const float*  vp = v + rbase*2048 + h*128 + vrow;
    const float*  ap = a + rbase*YSTRIDE + h*128 + vrow;
    const float*  bp = beta + rbase*YSTRIDE + h;
    float*        op = o + rbase*2048 + h*128 + vrow;

    float2 s = {0.f, 0.f};
    float2 kf[2][4], qf[2][4];
    float  vf[2][4], af4[2][4], bf4[2][4];

    #pragma unroll
    for (int j = 0; j < 4; j++) {
        kf[0][j] = kp[j*1024]; qf[0][j] = qp[j*1024];
        vf[0][j] = vp[(size_t)j*2048]; af4[0][j] = ap[(size_t)j*YSTRIDE]; bf4[0][j] = bp[(size_t)j*YSTRIDE];
    }

    #pragma unroll 1
    for (int t0 = 0; t0 < T_; t0 += 4) {
        const int buf = (t0 >> 2) & 1, nb = buf ^ 1;
        const int tn = t0 + 4;   // prefetch (may overrun into adjacent ws arrays; values unused)
        #pragma unroll
        for (int j = 0; j < 4; j++) {
            kf[nb][j] = kp[(tn+j)*1024]; qf[nb][j] = qp[(tn+j)*1024];
            vf[nb][j] = vp[(size_t)(tn+j)*2048];
            af4[nb][j] = ap[(size_t)(tn+j)*YSTRIDE];
            bf4[nb][j] = bp[(size_t)(tn+j)*YSTRIDE];
        }
        #pragma unroll
        for (int j = 0; j < 4; j++) {
            float2 kv = kf[buf][j], qv = qf[buf][j];
            float vt = vf[buf][j], at = af4[buf][j], bt = bf4[buf][j];
            float sk = fmaf(s.x, kv.x, s.y*kv.y);
            sk = wave_sum63(sk);
            float skt = __builtin_bit_cast(float, __builtin_amdgcn_readlane(__builtin_bit_cast(int, sk), 63));
            float c = bt * (skt - vt);
            s.x = fmaf(at, s.x, -c*kv.x);
            s.y = fmaf(at, s.y, -c*kv.y);
            float ov_ = fmaf(s.x, qv.x, s.y*qv.y);
            ov_ = wave_sum63(ov_);
            if (lane == 63) op[(size_t)(t0+j)*2048] = ov_;
        }
    }
}

// ---------------- LayerNorm over DV, * gate, -> bf16 ----------------
__global__ __launch_bounds__(256) void ln_gate_kernel(
    const float* __restrict__ o, const float* __restrict__ g, int g_stride,
    const float* __restrict__ ln_g, const float* __restrict__ ln_b,
    unsigned short* __restrict__ og)
{
    int wave = threadIdx.x >> 6, lane = threadIdx.x & 63;
    int gidx = blockIdx.x*4 + wave;     // 0..32767
    int row = gidx >> 4, h = gidx & 15;
    const float* ob = o + (size_t)row*2048 + h*128;
    int d0 = lane*2;
    float2 xv = *(const float2*)(ob + d0);
    float s = xv.x + xv.y, ss = xv.x*xv.x + xv.y*xv.y;
    for (int m = 1; m < 64; m <<= 1) { s += __shfl_xor(s, m); ss += __shfl_xor(ss, m); }
    float mu  = s * (1.f/128.f);
    float var = ss * (1.f/128.f) - mu*mu;
    float inv = rsqrtf(var + 1e-5f);
    const float* gb = g + (size_t)row*g_stride + h*128;
    float r0 = ((xv.x - mu)*inv*ln_g[d0]   + ln_b[d0])   * gb[d0];
    float r1 = ((xv.y - mu)*inv*ln_g[d0+1] + ln_b[d0+1]) * gb[d0+1];
    ushort2 u; u.x = f2bf(r0); u.y = f2bf(r1);
    *(ushort2*)(og + (size_t)row*2048 + h*128 + d0) = u;
}

extern "C" void kernel_launch(void* const* d_in, const int* in_sizes, int n_in,
                              void* d_out, int out_size, void* d_ws, size_t ws_size,
                              hipStream_t stream)
{
    const float* x   = (const float*)d_in[0];
    const float* Wq  = (const float*)d_in[1];
    const float* Wk  = (const float*)d_in[2];
    const float* Wv  = (const float*)d_in[3];
    const float* Wa  = (const float*)d_in[4];
    const float* ba  = (const float*)d_in[5];
    const float* Wb  = (const float*)d_in[6];
    const float* bb  = (const float*)d_in[7];
    const float* cqw = (const float*)d_in[8];
    const float* cqb = (const float*)d_in[9];
    const float* ckw = (const float*)d_in[10];
    const float* ckb = (const float*)d_in[11];
    const float* cvw = (const float*)d_in[12];
    const float* cvb = (const float*)d_in[13];
    const float* Wg  = (const float*)d_in[14];
    const float* lng = (const float*)d_in[15];
    const float* lnb = (const float*)d_in[16];
    const float* Wo  = (const float*)d_in[17];
    float* out = (float*)d_out;

    char* ws = (char*)d_ws;
    size_t off = 0;
    auto alloc = [&](size_t bytes){ void* p = ws + off; off += (bytes + 255) & ~(size_t)255; return p; };
    unsigned short* xb   = (unsigned short*)alloc((size_t)ROWS*D_*2);   // reused as og
    unsigned short* Wcat = (unsigned short*)alloc((size_t)NCAT*D_*2);
    unsigned short* Wob  = (unsigned short*)alloc((size_t)D_*D_*2);
    float* Y  = (float*)alloc((size_t)ROWS*YSTRIDE*4);
    float* qs = (float*)alloc((size_t)ROWS*2048*4);
    float* ks = (float*)alloc((size_t)ROWS*2048*4);
    float* vs = (float*)alloc((size_t)ROWS*2048*4);
    float* ov = (float*)alloc((size_t)ROWS*2048*4);
    unsigned short* og = xb;
    (void)ws_size;

    Cast8 cargs;
    cargs.p[0]=x; cargs.p[1]=Wq; cargs.p[2]=Wk; cargs.p[3]=Wv; cargs.p[4]=Wa;
    cargs.p[5]=Wg; cargs.p[6]=Wo; cargs.p[7]=Wb;
    cast_all_kernel<<<28928, 256, 0, stream>>>(cargs, xb, Wcat, Wob);

    // fused projections + beta: [2048,10368] = xb @ Wcat^T
    gemm_bt<<<dim3(81,16), 256, 0, stream>>>(xb, Wcat, Y, ROWS, NCAT, D_, 6144, ba, bb);

    const float kscale = 0.08838834764831845f;  // DK^-0.5
    conv_silu_kernel<<<128, 256, 0, stream>>>(Y, 0,    cqw, cqb, 1.0f,   qs);
    conv_silu_kernel<<<128, 256, 0, stream>>>(Y, 2048, ckw, ckb, kscale, ks);
    conv_silu_kernel<<<128, 256, 0, stream>>>(Y, 4096, cvw, cvb, 1.0f,   vs);

    recurrence_kernel<<<1024, 256, 0, stream>>>(qs, ks, vs, Y + 6144, Y + 10240, ov);

    ln_gate_kernel<<<8192, 256, 0, stream>>>(ov, Y + 8192, YSTRIDE, lng, lnb, og);

    gemm_bt<<<dim3(16,16), 256, 0, stream>>>(og, Wob, out, ROWS, D_, D_, 1<<30, nullptr, nullptr);
}

// Round 4
// 841.231 us; speedup vs baseline: 1.8430x; 1.8430x over previous
//
#include <hip/hip_runtime.h>
#include <hip/hip_bf16.h>
#include <cstdint>
#include <cstddef>

#define B_ 2
#define T_ 1024
#define D_ 2048
#define H_ 16
#define DK_ 128
#define DV_ 128
#define ROWS (B_*T_)      // 2048
// Y columns: [q 0:2048 | k 2048:4096 | v 4096:6144 | a 6144:8192 | g 8192:10240 | beta 10240:10256 | pad :10368]
#define NCAT 10368
#define YSTRIDE 10368

typedef __attribute__((ext_vector_type(8))) short bf16x8;
typedef __attribute__((ext_vector_type(4))) float f32x4;

__device__ inline unsigned short f2bf(float f){
    union { float f; unsigned int u; } v; v.f = f;
    unsigned int r = (v.u + 0x7fffu + ((v.u >> 16) & 1u)) >> 16;
    return (unsigned short)r;
}
__device__ inline float sigm(float x){ return 1.0f / (1.0f + __expf(-x)); }

// ---- DPP helpers ----
template<int CTRL>
__device__ __forceinline__ float dpp_add(float x){
    int t = __builtin_amdgcn_update_dpp(0, __builtin_bit_cast(int, x), CTRL, 0xf, 0xf, true);
    return x + __builtin_bit_cast(float, t);
}
// sum over all 64 lanes; result valid in lane 63
__device__ __forceinline__ float wave_sum63(float x){
    x = dpp_add<0x111>(x);   // row_shr:1
    x = dpp_add<0x112>(x);   // row_shr:2
    x = dpp_add<0x114>(x);   // row_shr:4
    x = dpp_add<0x118>(x);   // row_shr:8   lane15/31/47/63 = 16-sums
    x = dpp_add<0x142>(x);   // row_bcast15 lane31 = sum(0..31), lane63 = sum(32..63)
    x = dpp_add<0x143>(x);   // row_bcast31 lane63 = sum(0..63)
    return x;
}

__device__ __forceinline__ void gl2lds16(const void* g, void* l){
    __builtin_amdgcn_global_load_lds((const __attribute__((address_space(1))) void*)g,
                                     (__attribute__((address_space(3))) void*)l, 16, 0, 0);
}

// ---------------- fused fp32 -> bf16 casts (one launch) ----------------
struct Cast8 { const float* p[8]; };  // x, Wq, Wk, Wv, Wa, Wg, Wo, Wb
__global__ void cast_all_kernel(Cast8 args, unsigned short* __restrict__ xb,
                                unsigned short* __restrict__ Wcat,
                                unsigned short* __restrict__ Wob){
    int blk = blockIdx.x;
    if (blk >= 28704) {  // zero-pad rows 10256..10367 of Wcat
        int i = (blk - 28704)*1024 + threadIdx.x*4;
        *(ushort4*)(Wcat + (size_t)10256*2048 + i) = (ushort4){0,0,0,0};
        return;
    }
    const float* src; unsigned short* dst; int i;
    if (blk >= 28672) {  // Wb -> Wcat rows 10240..10255
        i = (blk - 28672)*1024 + threadIdx.x*4;
        src = args.p[7]; dst = Wcat + (size_t)10240*2048;
    } else {
        int seg = blk >> 12;
        i = (blk & 4095)*1024 + threadIdx.x*4;
        src = args.p[seg];
        if (seg == 0)      dst = xb;
        else if (seg <= 5) dst = Wcat + (size_t)(seg-1)*4194304;
        else               dst = Wob;
    }
    float4 f = *(const float4*)(src + i);
    ushort4 u; u.x = f2bf(f.x); u.y = f2bf(f.y); u.z = f2bf(f.z); u.w = f2bf(f.w);
    *(ushort4*)(dst + i) = u;
}

// ---------------- bf16 GEMM (m97-style): C[M,N] = A[M,K]*Bm[N,K]^T ----------------
__global__ __launch_bounds__(256) void gemm_bt(
    const unsigned short* __restrict__ A,
    const unsigned short* __restrict__ Bm,
    float* __restrict__ C, int M, int N, int K,
    int act_start, const float* __restrict__ ba, const float* __restrict__ bbeta)
{
    __shared__ __align__(16) unsigned short lA[128*32];
    __shared__ __align__(16) unsigned short lB[128*32];
    const int tid  = threadIdx.x;
    const int wave = tid >> 6, lane = tid & 63;
    const int quad = lane >> 4, l16 = lane & 15;
    const int wm = wave >> 1, wn = wave & 1;
    const int m0 = blockIdx.y * 128, n0 = blockIdx.x * 128;

    const unsigned short* gsrcA[2];
    const unsigned short* gsrcB[2];
    unsigned short* ldst[2];
    #pragma unroll
    for (int i = 0; i < 2; i++) {
        int chunk = wave*128 + i*64 + lane;
        int r = chunk >> 2, p = chunk & 3;
        int gcb = p ^ (r & 3);
        gsrcA[i] = A  + (size_t)(m0 + r)*K + gcb*8;
        gsrcB[i] = Bm + (size_t)(n0 + r)*K + gcb*8;
        ldst[i]  = (unsigned short*)((char*)lA + (size_t)(wave*128 + i*64)*16);
    }
    const size_t lBoff = (size_t)((char*)lB - (char*)lA);

    f32x4 acc[4][4];
    #pragma unroll
    for (int i = 0; i < 4; i++)
        #pragma unroll
        for (int j = 0; j < 4; j++) acc[i][j] = (f32x4){0.f,0.f,0.f,0.f};

    for (int k0 = 0; k0 < K; k0 += 32) {
        __syncthreads();
        #pragma unroll
        for (int i = 0; i < 2; i++) {
            gl2lds16(gsrcA[i] + k0, ldst[i]);
            gl2lds16(gsrcB[i] + k0, (char*)ldst[i] + lBoff);
        }
        __syncthreads();
        bf16x8 af[4], bfr[4];
        #pragma unroll
        for (int i = 0; i < 4; i++) {
            int ra = wm*64 + i*16 + l16;
            int rb = wn*64 + i*16 + l16;
            af[i]  = *(const bf16x8*)(&lA[ra*32 + ((quad ^ (ra & 3))*8)]);
            bfr[i] = *(const bf16x8*)(&lB[rb*32 + ((quad ^ (rb & 3))*8)]);
        }
        #pragma unroll
        for (int i = 0; i < 4; i++)
            #pragma unroll
            for (int j = 0; j < 4; j++)
                acc[i][j] = __builtin_amdgcn_mfma_f32_16x16x32_bf16(af[i], bfr[j], acc[i][j], 0, 0, 0);
    }

    #pragma unroll
    for (int i = 0; i < 4; i++) {
        int m = m0 + wm*64 + i*16 + quad*4;
        #pragma unroll
        for (int j = 0; j < 4; j++) {
            int n = n0 + wn*64 + j*16 + l16;
            #pragma unroll
            for (int r = 0; r < 4; r++) {
                float y = acc[i][j][r];
                if (n >= act_start) {
                    float bsum = 0.0f;
                    if (n < 8192) bsum = ba[n - 6144];
                    else if (n >= 10240 && n < 10256) bsum = bbeta[n - 10240];
                    y = sigm(y + bsum);
                }
                C[(size_t)(m + r)*N + n] = y;
            }
        }
    }
}

// ---------------- causal depthwise conv (K=4) + silu + scale ----------------
__global__ void conv_silu_kernel(const float* __restrict__ Y, int col_off,
                                 const float* __restrict__ cw, const float* __restrict__ cb,
                                 float scale, float* __restrict__ out)
{
    int gid = blockIdx.x * blockDim.x + threadIdx.x;  // 32768 total
    int c = gid & 2047;
    int tmp = gid >> 11;
    int tch = tmp & 7;
    int b = tmp >> 3;
    int t0 = tch * 128;
    const float w0 = cw[c*4+0], w1 = cw[c*4+1], w2 = cw[c*4+2], w3 = cw[c*4+3];
    const float bias = cb[c];
    const float* src = Y + (size_t)b*T_*YSTRIDE + col_off + c;
    float* dst = out + (size_t)b*T_*2048 + c;
    float y0 = (t0 >= 3) ? src[(size_t)(t0-3)*YSTRIDE] : 0.f;
    float y1 = (t0 >= 2) ? src[(size_t)(t0-2)*YSTRIDE] : 0.f;
    float y2 = (t0 >= 1) ? src[(size_t)(t0-1)*YSTRIDE] : 0.f;
    for (int t = t0; t < t0 + 128; t++) {
        float y3 = src[(size_t)t*YSTRIDE];
        float s = fmaf(w0,y0, fmaf(w1,y1, fmaf(w2,y2, fmaf(w3,y3, bias))));
        float r = s * (1.0f/(1.0f + __expf(-s))) * scale;
        dst[(size_t)t*2048] = r;
        y0 = y1; y1 = y2; y2 = y3;
    }
}

// ---------------- gated delta recurrence: 1 v-row per wave ----------------
// blk = rowgrp*32 + bh  ->  all 32 blocks of a (b,h) share XCD (bh % 8) for k/q L2 locality.
// Two explicit 4-step groups, ALL buffer indices compile-time (register-promoted).
__global__ __launch_bounds__(256) void recurrence_kernel(
    const float* __restrict__ q, const float* __restrict__ k, const float* __restrict__ v,
    const float* __restrict__ a, const float* __restrict__ beta, float* __restrict__ o)
{
    const int blk = blockIdx.x;
    const int bh = blk & 31;
    const int rowgrp = blk >> 5;
    const int h = bh & 15, b = bh >> 4;
    const int lane = threadIdx.x & 63;
    const int wave = threadIdx.x >> 6;
    const int vrow = rowgrp*4 + wave;     // 0..127
    const size_t rbase = (size_t)b * T_;
    const float2* kp = (const float2*)(k + rbase*2048 + (size_t)h*128) + lane;  // step stride 1024 float2
    const float2* qp = (const float2*)(q + rbase*2048 + (size_t)h*128) + lane;
    const float*  vp = v + rbase*2048 + h*128 + vrow;
    const float*  ap = a + rbase*YSTRIDE + h*128 + vrow;
    const float*  bp = beta + rbase*YSTRIDE + h;
    float*        op = o + rbase*2048 + h*128 + vrow;

    float2 s = {0.f, 0.f};
    float2 kc[4], qc[4], kn[4], qn[4];
    float  vc[4], ac[4], bc[4], vn[4], an[4], bn[4];

    #pragma unroll
    for (int j = 0; j < 4; j++) {
        kc[j] = kp[j*1024]; qc[j] = qp[j*1024];
        vc[j] = vp[(size_t)j*2048]; ac[j] = ap[(size_t)j*YSTRIDE]; bc[j] = bp[(size_t)j*YSTRIDE];
    }

#define RSTEP(kv, qv, vt, at, bt, oidx) { \
    float sk = fmaf(s.x,(kv).x, s.y*(kv).y); \
    sk = wave_sum63(sk); \
    float skt = __builtin_bit_cast(float, __builtin_amdgcn_readlane(__builtin_bit_cast(int, sk), 63)); \
    float c = (bt) * (skt - (vt)); \
    s.x = fmaf((at), s.x, -c*(kv).x); \
    s.y = fmaf((at), s.y, -c*(kv).y); \
    float ov_ = fmaf(s.x,(qv).x, s.y*(qv).y); \
    ov_ = wave_sum63(ov_); \
    if (lane == 63) op[(size_t)(oidx)*2048] = ov_; \
}

    #pragma unroll 1
    for (int t0 = 0; t0 < T_; t0 += 8) {
        // prefetch t0+4..7 (group n)
        #pragma unroll
        for (int j = 0; j < 4; j++) {
            int t = t0 + 4 + j;
            kn[j] = kp[t*1024]; qn[j] = qp[t*1024];
            vn[j] = vp[(size_t)t*2048]; an[j] = ap[(size_t)t*YSTRIDE]; bn[j] = bp[(size_t)t*YSTRIDE];
        }
        // compute group c at t0..t0+3
        #pragma unroll
        for (int j = 0; j < 4; j++) RSTEP(kc[j], qc[j], vc[j], ac[j], bc[j], t0+j);
        // prefetch t0+8..11 into group c (last iter overruns into adjacent ws arrays; values unused)
        #pragma unroll
        for (int j = 0; j < 4; j++) {
            int t = t0 + 8 + j;
            kc[j] = kp[t*1024]; qc[j] = qp[t*1024];
            vc[j] = vp[(size_t)t*2048]; ac[j] = ap[(size_t)t*YSTRIDE]; bc[j] = bp[(size_t)t*YSTRIDE];
        }
        // compute group n at t0+4..t0+7
        #pragma unroll
        for (int j = 0; j < 4; j++) RSTEP(kn[j], qn[j], vn[j], an[j], bn[j], t0+4+j);
    }
#undef RSTEP
}

// ---------------- LayerNorm over DV, * gate, -> bf16 ----------------
__global__ __launch_bounds__(256) void ln_gate_kernel(
    const float* __restrict__ o, const float* __restrict__ g, int g_stride,
    const float* __restrict__ ln_g, const float* __restrict__ ln_b,
    unsigned short* __restrict__ og)
{
    int wave = threadIdx.x >> 6, lane = threadIdx.x & 63;
    int gidx = blockIdx.x*4 + wave;     // 0..32767
    int row = gidx >> 4, h = gidx & 15;
    const float* ob = o + (size_t)row*2048 + h*128;
    int d0 = lane*2;
    float2 xv = *(const float2*)(ob + d0);
    float s = xv.x + xv.y, ss = xv.x*xv.x + xv.y*xv.y;
    for (int m = 1; m < 64; m <<= 1) { s += __shfl_xor(s, m); ss += __shfl_xor(ss, m); }
    float mu  = s * (1.f/128.f);
    float var = ss * (1.f/128.f) - mu*mu;
    float inv = rsqrtf(var + 1e-5f);
    const float* gb = g + (size_t)row*g_stride + h*128;
    float r0 = ((xv.x - mu)*inv*ln_g[d0]   + ln_b[d0])   * gb[d0];
    float r1 = ((xv.y - mu)*inv*ln_g[d0+1] + ln_b[d0+1]) * gb[d0+1];
    ushort2 u; u.x = f2bf(r0); u.y = f2bf(r1);
    *(ushort2*)(og + (size_t)row*2048 + h*128 + d0) = u;
}

extern "C" void kernel_launch(void* const* d_in, const int* in_sizes, int n_in,
                              void* d_out, int out_size, void* d_ws, size_t ws_size,
                              hipStream_t stream)
{
    const float* x   = (const float*)d_in[0];
    const float* Wq  = (const float*)d_in[1];
    const float* Wk  = (const float*)d_in[2];
    const float* Wv  = (const float*)d_in[3];
    const float* Wa  = (const float*)d_in[4];
    const float* ba  = (const float*)d_in[5];
    const float* Wb  = (const float*)d_in[6];
    const float* bb  = (const float*)d_in[7];
    const float* cqw = (const float*)d_in[8];
    const float* cqb = (const float*)d_in[9];
    const float* ckw = (const float*)d_in[10];
    const float* ckb = (const float*)d_in[11];
    const float* cvw = (const float*)d_in[12];
    const float* cvb = (const float*)d_in[13];
    const float* Wg  = (const float*)d_in[14];
    const float* lng = (const float*)d_in[15];
    const float* lnb = (const float*)d_in[16];
    const float* Wo  = (const float*)d_in[17];
    float* out = (float*)d_out;

    char* ws = (char*)d_ws;
    size_t off = 0;
    auto alloc = [&](size_t bytes){ void* p = ws + off; off += (bytes + 255) & ~(size_t)255; return p; };
    unsigned short* xb   = (unsigned short*)alloc((size_t)ROWS*D_*2);   // reused as og
    unsigned short* Wcat = (unsigned short*)alloc((size_t)NCAT*D_*2);
    unsigned short* Wob  = (unsigned short*)alloc((size_t)D_*D_*2);
    float* Y  = (float*)alloc((size_t)ROWS*YSTRIDE*4);
    float* qs = (float*)alloc((size_t)ROWS*2048*4);
    float* ks = (float*)alloc((size_t)ROWS*2048*4);
    float* vs = (float*)alloc((size_t)ROWS*2048*4);
    float* ov = (float*)alloc((size_t)ROWS*2048*4);
    unsigned short* og = xb;
    (void)ws_size;

    Cast8 cargs;
    cargs.p[0]=x; cargs.p[1]=Wq; cargs.p[2]=Wk; cargs.p[3]=Wv; cargs.p[4]=Wa;
    cargs.p[5]=Wg; cargs.p[6]=Wo; cargs.p[7]=Wb;
    cast_all_kernel<<<28928, 256, 0, stream>>>(cargs, xb, Wcat, Wob);

    // fused projections + beta: [2048,10368] = xb @ Wcat^T
    gemm_bt<<<dim3(81,16), 256, 0, stream>>>(xb, Wcat, Y, ROWS, NCAT, D_, 6144, ba, bb);

    const float kscale = 0.08838834764831845f;  // DK^-0.5
    conv_silu_kernel<<<128, 256, 0, stream>>>(Y, 0,    cqw, cqb, 1.0f,   qs);
    conv_silu_kernel<<<128, 256, 0, stream>>>(Y, 2048, ckw, ckb, kscale, ks);
    conv_silu_kernel<<<128, 256, 0, stream>>>(Y, 4096, cvw, cvb, 1.0f,   vs);

    recurrence_kernel<<<1024, 256, 0, stream>>>(qs, ks, vs, Y + 6144, Y + 10240, ov);

    ln_gate_kernel<<<8192, 256, 0, stream>>>(ov, Y + 8192, YSTRIDE, lng, lnb, og);

    gemm_bt<<<dim3(16,16), 256, 0, stream>>>(og, Wob, out, ROWS, D_, D_, 1<<30, nullptr, nullptr);
}